// Round 1
// baseline (3680.611 us; speedup 1.0000x reference)
//
#include <hip/hip_runtime.h>

#define DIMS 64

// ---------------------------------------------------------------------------
// E = concat(U_emb, V_emb), vectorized float4 (both sections are %4 elems)
// ---------------------------------------------------------------------------
__global__ __launch_bounds__(256) void init_e_kernel(
    const float* __restrict__ U, const float* __restrict__ V,
    float* __restrict__ E, int nU_elems, int total_elems) {
  int i = (blockIdx.x * blockDim.x + threadIdx.x) * 4;
  if (i >= total_elems) return;
  float4 v = (i < nU_elems)
      ? *reinterpret_cast<const float4*>(U + i)
      : *reinterpret_cast<const float4*>(V + (i - nU_elems));
  *reinterpret_cast<float4*>(E + i) = v;
}

// ---------------------------------------------------------------------------
// CSR build: histogram -> single-block chunked scan -> scatter
// ---------------------------------------------------------------------------
__global__ __launch_bounds__(256) void hist_kernel(
    const int* __restrict__ rows, int* __restrict__ cnt, int nnz) {
  int i = blockIdx.x * blockDim.x + threadIdx.x;
  if (i < nnz) atomicAdd(&cnt[rows[i]], 1);
}

__global__ __launch_bounds__(256) void scan_kernel(
    const int* __restrict__ cnt, int* __restrict__ row_ptr,
    int* __restrict__ cursor, int n) {
  __shared__ int tmp[256];
  __shared__ int s_carry;
  if (threadIdx.x == 0) s_carry = 0;
  __syncthreads();
  for (int base = 0; base < n; base += 256) {
    int idx = base + threadIdx.x;
    int v = (idx < n) ? cnt[idx] : 0;
    tmp[threadIdx.x] = v;
    __syncthreads();
    // Hillis-Steele inclusive scan over the 256-chunk
    for (int offs = 1; offs < 256; offs <<= 1) {
      int t = (threadIdx.x >= offs) ? tmp[threadIdx.x - offs] : 0;
      __syncthreads();
      tmp[threadIdx.x] += t;
      __syncthreads();
    }
    int incl = tmp[threadIdx.x];
    int chunk_total = tmp[255];
    int carry = s_carry;
    if (idx < n) {
      int excl = carry + incl - v;
      row_ptr[idx] = excl;
      cursor[idx]  = excl;
    }
    __syncthreads();
    if (threadIdx.x == 0) s_carry = carry + chunk_total;
    __syncthreads();
  }
  if (threadIdx.x == 0) row_ptr[n] = s_carry;
}

__global__ __launch_bounds__(256) void scatter_kernel(
    const int* __restrict__ rows, const int* __restrict__ cols,
    const float* __restrict__ vals, int* __restrict__ cursor,
    int* __restrict__ csr_cols, float* __restrict__ csr_vals, int nnz) {
  int i = blockIdx.x * blockDim.x + threadIdx.x;
  if (i >= nnz) return;
  int r = rows[i];
  int p = atomicAdd(&cursor[r], 1);
  csr_cols[p] = cols[i];
  csr_vals[p] = vals[i];
}

// ---------------------------------------------------------------------------
// SpMM: one wave per row, lane = dim. Gather of cur[col*64+lane] is a fully
// contiguous 256B wave read; cur (76.8MB) is Infinity-Cache resident.
// ---------------------------------------------------------------------------
__global__ __launch_bounds__(256) void spmm_kernel(
    const int* __restrict__ row_ptr, const int* __restrict__ csr_cols,
    const float* __restrict__ csr_vals, const float* __restrict__ cur,
    float* __restrict__ next, int n_rows) {
  int row  = blockIdx.x * (blockDim.x >> 6) + (threadIdx.x >> 6);
  int lane = threadIdx.x & 63;
  if (row >= n_rows) return;
  int start = row_ptr[row];
  int end   = row_ptr[row + 1];
  float acc = 0.0f;
  int e = start;
  for (; e + 4 <= end; e += 4) {
    int   c0 = csr_cols[e],     c1 = csr_cols[e + 1];
    int   c2 = csr_cols[e + 2], c3 = csr_cols[e + 3];
    float v0 = csr_vals[e],     v1 = csr_vals[e + 1];
    float v2 = csr_vals[e + 2], v3 = csr_vals[e + 3];
    acc = fmaf(v0, cur[c0 * DIMS + lane], acc);
    acc = fmaf(v1, cur[c1 * DIMS + lane], acc);
    acc = fmaf(v2, cur[c2 * DIMS + lane], acc);
    acc = fmaf(v3, cur[c3 * DIMS + lane], acc);
  }
  for (; e < end; ++e)
    acc = fmaf(csr_vals[e], cur[csr_cols[e] * DIMS + lane], acc);
  next[row * DIMS + lane] = acc;
}

// ---------------------------------------------------------------------------
// Per-layer gather of the 8192 batch nodes into small accumulators
// ---------------------------------------------------------------------------
__global__ __launch_bounds__(256) void gather_kernel(
    const int* __restrict__ u, const int* __restrict__ it,
    const float* __restrict__ cur, float* __restrict__ accU,
    float* __restrict__ accI, int batch, int nU) {
  int b    = blockIdx.x * (blockDim.x >> 6) + (threadIdx.x >> 6);
  int lane = threadIdx.x & 63;
  if (b >= batch) return;
  accU[b * DIMS + lane] += cur[u[b] * DIMS + lane];
  accI[b * DIMS + lane] += cur[(it[b] + nU) * DIMS + lane];
}

// ---------------------------------------------------------------------------
// score[b] = dot(accU[b], accI[b]) / 16   ((L+1)^2 = 16)
// ---------------------------------------------------------------------------
__global__ __launch_bounds__(256) void score_kernel(
    const float* __restrict__ accU, const float* __restrict__ accI,
    float* __restrict__ out, int batch) {
  int b    = blockIdx.x * (blockDim.x >> 6) + (threadIdx.x >> 6);
  int lane = threadIdx.x & 63;
  if (b >= batch) return;
  float v = accU[b * DIMS + lane] * accI[b * DIMS + lane];
  for (int offs = 32; offs > 0; offs >>= 1) v += __shfl_down(v, offs, 64);
  if (lane == 0) out[b] = v * (1.0f / 16.0f);
}

// ---------------------------------------------------------------------------
extern "C" void kernel_launch(void* const* d_in, const int* in_sizes, int n_in,
                              void* d_out, int out_size, void* d_ws, size_t ws_size,
                              hipStream_t stream) {
  const int*   u     = (const int*)d_in[0];
  const int*   it    = (const int*)d_in[1];
  const int*   arows = (const int*)d_in[2];
  const int*   acols = (const int*)d_in[3];
  const float* avals = (const float*)d_in[4];
  const float* U     = (const float*)d_in[5];
  const float* V     = (const float*)d_in[6];

  const int batch = in_sizes[0];
  const int nnz   = in_sizes[2];
  const int nU    = in_sizes[5] / DIMS;
  const int nV    = in_sizes[6] / DIMS;
  const int N     = nU + nV;

  char*  ws  = (char*)d_ws;
  size_t off = 0;
  auto take = [&](size_t bytes) -> void* {
    void* p = ws + off;
    off = (off + bytes + 255) & ~(size_t)255;
    return p;
  };
  int*   cnt      = (int*)take((size_t)N * 4);
  int*   cursor   = (int*)take((size_t)N * 4);
  int*   row_ptr  = (int*)take((size_t)(N + 1) * 4);
  int*   csr_cols = (int*)take((size_t)nnz * 4);
  float* csr_vals = (float*)take((size_t)nnz * 4);
  float* bufA     = (float*)take((size_t)N * DIMS * 4);
  float* bufB     = (float*)take((size_t)N * DIMS * 4);
  float* accU     = (float*)take((size_t)batch * DIMS * 4);
  float* accI     = (float*)take((size_t)batch * DIMS * 4);

  hipMemsetAsync(cnt,  0, (size_t)N * 4, stream);
  hipMemsetAsync(accU, 0, (size_t)batch * DIMS * 4, stream);
  hipMemsetAsync(accI, 0, (size_t)batch * DIMS * 4, stream);

  {
    int total = N * DIMS;
    int t4 = total / 4;
    init_e_kernel<<<(t4 + 255) / 256, 256, 0, stream>>>(U, V, bufA, nU * DIMS, total);
  }

  hist_kernel<<<(nnz + 255) / 256, 256, 0, stream>>>(arows, cnt, nnz);
  scan_kernel<<<1, 256, 0, stream>>>(cnt, row_ptr, cursor, N);
  scatter_kernel<<<(nnz + 255) / 256, 256, 0, stream>>>(arows, acols, avals, cursor,
                                                        csr_cols, csr_vals, nnz);

  // E0 contribution to the batch accumulators
  gather_kernel<<<(batch + 3) / 4, 256, 0, stream>>>(u, it, bufA, accU, accI, batch, nU);

  float* cur = bufA;
  float* nxt = bufB;
  for (int layer = 0; layer < 3; ++layer) {
    spmm_kernel<<<(N + 3) / 4, 256, 0, stream>>>(row_ptr, csr_cols, csr_vals, cur, nxt, N);
    gather_kernel<<<(batch + 3) / 4, 256, 0, stream>>>(u, it, nxt, accU, accI, batch, nU);
    float* t = cur; cur = nxt; nxt = t;
  }

  score_kernel<<<(batch + 3) / 4, 256, 0, stream>>>(accU, accI, (float*)d_out, batch);
}

// Round 2
// 2279.276 us; speedup vs baseline: 1.6148x; 1.6148x over previous
//
#include <hip/hip_runtime.h>

#define DIMS 64
#define SCAN_CHUNK 2048  // 256 threads * 8 elems

// ---------------------------------------------------------------------------
// E = concat(U_emb, V_emb), vectorized float4 (both sections are %4 elems)
// ---------------------------------------------------------------------------
__global__ __launch_bounds__(256) void init_e_kernel(
    const float* __restrict__ U, const float* __restrict__ V,
    float* __restrict__ E, int nU_elems, int total_elems) {
  int i = (blockIdx.x * blockDim.x + threadIdx.x) * 4;
  if (i >= total_elems) return;
  float4 v = (i < nU_elems)
      ? *reinterpret_cast<const float4*>(U + i)
      : *reinterpret_cast<const float4*>(V + (i - nU_elems));
  *reinterpret_cast<float4*>(E + i) = v;
}

// ---------------------------------------------------------------------------
// CSR build: histogram -> 3-phase parallel scan -> scatter
// ---------------------------------------------------------------------------
__global__ __launch_bounds__(256) void hist_kernel(
    const int* __restrict__ rows, int* __restrict__ cnt, int nnz) {
  int i = blockIdx.x * blockDim.x + threadIdx.x;
  if (i < nnz) atomicAdd(&cnt[rows[i]], 1);
}

// phase1: per-block chunk reduction
__global__ __launch_bounds__(256) void scan_phase1(
    const int* __restrict__ cnt, int* __restrict__ block_sums, int n) {
  __shared__ int sdata[256];
  int base = blockIdx.x * SCAN_CHUNK;
  int sum = 0;
#pragma unroll
  for (int k = 0; k < 8; ++k) {
    int idx = base + k * 256 + threadIdx.x;
    if (idx < n) sum += cnt[idx];
  }
  sdata[threadIdx.x] = sum;
  __syncthreads();
  for (int s = 128; s > 0; s >>= 1) {
    if (threadIdx.x < s) sdata[threadIdx.x] += sdata[threadIdx.x + s];
    __syncthreads();
  }
  if (threadIdx.x == 0) block_sums[blockIdx.x] = sdata[0];
}

// phase2: single 256-wide exclusive scan over block sums (n_blocks <= 256);
// also writes row_ptr[n] = total nnz
__global__ __launch_bounds__(256) void scan_phase2(
    int* __restrict__ block_sums, int n_blocks, int* __restrict__ row_ptr, int n) {
  __shared__ int tmp[256];
  int v = (threadIdx.x < n_blocks) ? block_sums[threadIdx.x] : 0;
  tmp[threadIdx.x] = v;
  __syncthreads();
  for (int offs = 1; offs < 256; offs <<= 1) {
    int t = (threadIdx.x >= offs) ? tmp[threadIdx.x - offs] : 0;
    __syncthreads();
    tmp[threadIdx.x] += t;
    __syncthreads();
  }
  if (threadIdx.x < n_blocks) block_sums[threadIdx.x] = tmp[threadIdx.x] - v;  // exclusive
  if (threadIdx.x == 0) row_ptr[n] = tmp[255];  // total
}

// phase3: per-block chunk scan with offset, writes row_ptr and cursor
__global__ __launch_bounds__(256) void scan_phase3(
    const int* __restrict__ cnt, const int* __restrict__ block_sums,
    int* __restrict__ row_ptr, int* __restrict__ cursor, int n) {
  __shared__ int tmp[256];
  __shared__ int s_carry;
  int base = blockIdx.x * SCAN_CHUNK;
  if (threadIdx.x == 0) s_carry = block_sums[blockIdx.x];
  __syncthreads();
#pragma unroll 1
  for (int k = 0; k < 8; ++k) {
    int idx = base + k * 256 + threadIdx.x;
    int v = (idx < n) ? cnt[idx] : 0;
    tmp[threadIdx.x] = v;
    __syncthreads();
    for (int offs = 1; offs < 256; offs <<= 1) {
      int t = (threadIdx.x >= offs) ? tmp[threadIdx.x - offs] : 0;
      __syncthreads();
      tmp[threadIdx.x] += t;
      __syncthreads();
    }
    int incl = tmp[threadIdx.x];
    int carry = s_carry;
    if (idx < n) {
      int excl = carry + incl - v;
      row_ptr[idx] = excl;
      cursor[idx]  = excl;
    }
    __syncthreads();
    if (threadIdx.x == 0) s_carry = carry + tmp[255];
    __syncthreads();
  }
}

__global__ __launch_bounds__(256) void scatter_kernel(
    const int* __restrict__ rows, const int* __restrict__ cols,
    const float* __restrict__ vals, int* __restrict__ cursor,
    int* __restrict__ csr_cols, float* __restrict__ csr_vals, int nnz) {
  int i = blockIdx.x * blockDim.x + threadIdx.x;
  if (i >= nnz) return;
  int r = rows[i];
  int p = atomicAdd(&cursor[r], 1);
  csr_cols[p] = cols[i];
  csr_vals[p] = vals[i];
}

// ---------------------------------------------------------------------------
// SpMM: one wave per row, lane = dim. Gather of cur[col*64+lane] is a fully
// contiguous 256B wave read; cur (76.8MB) is Infinity-Cache resident.
// ---------------------------------------------------------------------------
__global__ __launch_bounds__(256) void spmm_kernel(
    const int* __restrict__ row_ptr, const int* __restrict__ csr_cols,
    const float* __restrict__ csr_vals, const float* __restrict__ cur,
    float* __restrict__ next, int n_rows) {
  int row  = blockIdx.x * (blockDim.x >> 6) + (threadIdx.x >> 6);
  int lane = threadIdx.x & 63;
  if (row >= n_rows) return;
  int start = row_ptr[row];
  int end   = row_ptr[row + 1];
  float acc = 0.0f;
  int e = start;
  for (; e + 4 <= end; e += 4) {
    int   c0 = csr_cols[e],     c1 = csr_cols[e + 1];
    int   c2 = csr_cols[e + 2], c3 = csr_cols[e + 3];
    float v0 = csr_vals[e],     v1 = csr_vals[e + 1];
    float v2 = csr_vals[e + 2], v3 = csr_vals[e + 3];
    acc = fmaf(v0, cur[c0 * DIMS + lane], acc);
    acc = fmaf(v1, cur[c1 * DIMS + lane], acc);
    acc = fmaf(v2, cur[c2 * DIMS + lane], acc);
    acc = fmaf(v3, cur[c3 * DIMS + lane], acc);
  }
  for (; e < end; ++e)
    acc = fmaf(csr_vals[e], cur[csr_cols[e] * DIMS + lane], acc);
  next[row * DIMS + lane] = acc;
}

// ---------------------------------------------------------------------------
// Per-layer gather of the 8192 batch nodes into small accumulators
// ---------------------------------------------------------------------------
__global__ __launch_bounds__(256) void gather_kernel(
    const int* __restrict__ u, const int* __restrict__ it,
    const float* __restrict__ cur, float* __restrict__ accU,
    float* __restrict__ accI, int batch, int nU) {
  int b    = blockIdx.x * (blockDim.x >> 6) + (threadIdx.x >> 6);
  int lane = threadIdx.x & 63;
  if (b >= batch) return;
  accU[b * DIMS + lane] += cur[u[b] * DIMS + lane];
  accI[b * DIMS + lane] += cur[(it[b] + nU) * DIMS + lane];
}

// ---------------------------------------------------------------------------
// score[b] = dot(accU[b], accI[b]) / 16   ((L+1)^2 = 16)
// ---------------------------------------------------------------------------
__global__ __launch_bounds__(256) void score_kernel(
    const float* __restrict__ accU, const float* __restrict__ accI,
    float* __restrict__ out, int batch) {
  int b    = blockIdx.x * (blockDim.x >> 6) + (threadIdx.x >> 6);
  int lane = threadIdx.x & 63;
  if (b >= batch) return;
  float v = accU[b * DIMS + lane] * accI[b * DIMS + lane];
  for (int offs = 32; offs > 0; offs >>= 1) v += __shfl_down(v, offs, 64);
  if (lane == 0) out[b] = v * (1.0f / 16.0f);
}

// ---------------------------------------------------------------------------
extern "C" void kernel_launch(void* const* d_in, const int* in_sizes, int n_in,
                              void* d_out, int out_size, void* d_ws, size_t ws_size,
                              hipStream_t stream) {
  const int*   u     = (const int*)d_in[0];
  const int*   it    = (const int*)d_in[1];
  const int*   arows = (const int*)d_in[2];
  const int*   acols = (const int*)d_in[3];
  const float* avals = (const float*)d_in[4];
  const float* U     = (const float*)d_in[5];
  const float* V     = (const float*)d_in[6];

  const int batch = in_sizes[0];
  const int nnz   = in_sizes[2];
  const int nU    = in_sizes[5] / DIMS;
  const int nV    = in_sizes[6] / DIMS;
  const int N     = nU + nV;
  const int n_scan_blocks = (N + SCAN_CHUNK - 1) / SCAN_CHUNK;  // 147 < 256

  char*  ws  = (char*)d_ws;
  size_t off = 0;
  auto take = [&](size_t bytes) -> void* {
    void* p = ws + off;
    off = (off + bytes + 255) & ~(size_t)255;
    return p;
  };
  int*   cnt        = (int*)take((size_t)N * 4);
  int*   cursor     = (int*)take((size_t)N * 4);
  int*   row_ptr    = (int*)take((size_t)(N + 1) * 4);
  int*   block_sums = (int*)take((size_t)256 * 4);
  int*   csr_cols   = (int*)take((size_t)nnz * 4);
  float* csr_vals   = (float*)take((size_t)nnz * 4);
  float* bufA       = (float*)take((size_t)N * DIMS * 4);
  float* bufB       = (float*)take((size_t)N * DIMS * 4);
  float* accU       = (float*)take((size_t)batch * DIMS * 4);
  float* accI       = (float*)take((size_t)batch * DIMS * 4);

  hipMemsetAsync(cnt,  0, (size_t)N * 4, stream);
  hipMemsetAsync(accU, 0, (size_t)batch * DIMS * 4, stream);
  hipMemsetAsync(accI, 0, (size_t)batch * DIMS * 4, stream);

  {
    int total = N * DIMS;
    int t4 = total / 4;
    init_e_kernel<<<(t4 + 255) / 256, 256, 0, stream>>>(U, V, bufA, nU * DIMS, total);
  }

  hist_kernel<<<(nnz + 255) / 256, 256, 0, stream>>>(arows, cnt, nnz);
  scan_phase1<<<n_scan_blocks, 256, 0, stream>>>(cnt, block_sums, N);
  scan_phase2<<<1, 256, 0, stream>>>(block_sums, n_scan_blocks, row_ptr, N);
  scan_phase3<<<n_scan_blocks, 256, 0, stream>>>(cnt, block_sums, row_ptr, cursor, N);
  scatter_kernel<<<(nnz + 255) / 256, 256, 0, stream>>>(arows, acols, avals, cursor,
                                                        csr_cols, csr_vals, nnz);

  // E0 contribution to the batch accumulators
  gather_kernel<<<(batch + 3) / 4, 256, 0, stream>>>(u, it, bufA, accU, accI, batch, nU);

  float* cur = bufA;
  float* nxt = bufB;
  for (int layer = 0; layer < 3; ++layer) {
    spmm_kernel<<<(N + 3) / 4, 256, 0, stream>>>(row_ptr, csr_cols, csr_vals, cur, nxt, N);
    gather_kernel<<<(batch + 3) / 4, 256, 0, stream>>>(u, it, nxt, accU, accI, batch, nU);
    float* t = cur; cur = nxt; nxt = t;
  }

  score_kernel<<<(batch + 3) / 4, 256, 0, stream>>>(accU, accI, (float*)d_out, batch);
}